// Round 1
// baseline (846.846 us; speedup 1.0000x reference)
//
#include <hip/hip_runtime.h>
#include <math.h>

#define B_  32
#define NA_ 32768
#define C_  81
#define NG_ 24

// ---------- helpers ----------
__device__ inline float wave_max_f(float v) {
  #pragma unroll
  for (int s = 32; s >= 1; s >>= 1) v = fmaxf(v, __shfl_xor(v, s));
  return v;
}
__device__ inline float wave_sum_f(float v) {
  #pragma unroll
  for (int s = 32; s >= 1; s >>= 1) v += __shfl_xor(v, s);
  return v;
}
__device__ inline unsigned long long shflx_u64(unsigned long long v, int s) {
  int lo = __shfl_xor((int)(unsigned)(v & 0xFFFFFFFFULL), s);
  int hi = __shfl_xor((int)(unsigned)(v >> 32), s);
  return ((unsigned long long)(unsigned)hi << 32) | (unsigned)lo;
}

// ---------- K0: zero accumulators (ws is poisoned 0xAA each call) ----------
__global__ void k_init(unsigned long long* best_packed, int* num_pos_g, int* notneg_g,
                       float* pos_ce_g, float* reg_sum_g) {
  const int t = threadIdx.x + blockIdx.x * blockDim.x;
  if (t < B_ * NG_) best_packed[t] = 0ULL;
  if (t < B_) { num_pos_g[t] = 0; notneg_g[t] = 0; pos_ce_g[t] = 0.f; reg_sum_g[t] = 0.f; }
}

// ---------- K1: per-anchor IoU max/argmax + per-GT best anchor ----------
__global__ __launch_bounds__(256) void k_match(
    const float* __restrict__ anchors, const float* __restrict__ gt_boxes,
    float* __restrict__ iou_max_out, int* __restrict__ gt_idx_out,
    unsigned long long* __restrict__ best_packed)
{
  const int b = blockIdx.y;
  const int a = blockIdx.x * 256 + threadIdx.x;
  __shared__ float4 gt_sh[NG_];
  __shared__ float gt_area_sh[NG_];
  __shared__ unsigned long long best_sh[NG_];
  if (threadIdx.x < NG_) {
    const float* g = gt_boxes + ((size_t)b * NG_ + threadIdx.x) * 4;
    float cx = g[0], cy = g[1], w = g[2], h = g[3];
    float x0 = cx - 0.5f * w, y0 = cy - 0.5f * h, x1 = cx + 0.5f * w, y1 = cy + 0.5f * h;
    gt_sh[threadIdx.x] = make_float4(x0, y0, x1, y1);
    gt_area_sh[threadIdx.x] = (x1 - x0) * (y1 - y0);
    best_sh[threadIdx.x] = 0ULL;
  }
  __syncthreads();
  const float4 anc = ((const float4*)anchors)[a];
  const float ax0 = anc.x - 0.5f * anc.z, ay0 = anc.y - 0.5f * anc.w;
  const float ax1 = anc.x + 0.5f * anc.z, ay1 = anc.y + 0.5f * anc.w;
  const float area_a = (ax1 - ax0) * (ay1 - ay0);
  float best_iou = -1.0f; int best_g = 0;
  const int lane = threadIdx.x & 63;
  for (int g = 0; g < NG_; ++g) {
    const float4 G = gt_sh[g];
    float lx = fmaxf(ax0, G.x), ly = fmaxf(ay0, G.y);
    float rx = fminf(ax1, G.z), ry = fminf(ay1, G.w);
    float ww = fmaxf(rx - lx, 0.f), hh = fmaxf(ry - ly, 0.f);
    float inter = ww * hh;
    float uni = area_a + gt_area_sh[g] - inter;
    float iou = inter / fmaxf(uni, 1e-12f);
    if (iou > best_iou) { best_iou = iou; best_g = g; }   // first-max tie-break
    // max iou; ties -> smallest anchor index (max of ~a)
    unsigned long long key =
        ((unsigned long long)__float_as_uint(iou) << 32) | (unsigned)(~(unsigned)a);
    #pragma unroll
    for (int s = 32; s >= 1; s >>= 1) {
      unsigned long long o = shflx_u64(key, s);
      if (o > key) key = o;
    }
    if (lane == 0) atomicMax(&best_sh[g], key);
  }
  const size_t idx = (size_t)b * NA_ + a;
  iou_max_out[idx] = best_iou;
  gt_idx_out[idx]  = best_g;
  __syncthreads();
  if (threadIdx.x < NG_)
    atomicMax(&best_packed[b * NG_ + threadIdx.x], best_sh[threadIdx.x]);
}

// ---------- K2: classify anchors, CE (wave per anchor), reg loss ----------
#define APW 16   // anchors per wave; block = 4 waves -> 64 anchors/block
__global__ __launch_bounds__(256) void k_ce(
    const float* __restrict__ cls_pred, const float* __restrict__ box_pred,
    const float* __restrict__ anchors, const float* __restrict__ gt_boxes,
    const int* __restrict__ gt_labels,
    const float* __restrict__ iou_max_in, const int* __restrict__ gt_idx_in,
    const unsigned long long* __restrict__ best_packed,
    int* __restrict__ neg_bits,
    int* __restrict__ num_pos_g, int* __restrict__ notneg_g,
    float* __restrict__ pos_ce_g, float* __restrict__ reg_sum_g)
{
  const int b = blockIdx.y;
  const int wave = threadIdx.x >> 6, lane = threadIdx.x & 63;
  __shared__ int best_a_sh[NG_];
  __shared__ int label_sh[NG_];
  __shared__ int np_sh[4], nn_sh[4];
  __shared__ float pce_sh[4], reg_sh[4];
  if (threadIdx.x < NG_) {
    best_a_sh[threadIdx.x] = (int)(~(unsigned)(best_packed[b * NG_ + threadIdx.x]));
    label_sh[threadIdx.x]  = gt_labels[b * NG_ + threadIdx.x];
  }
  __syncthreads();
  const int base = blockIdx.x * (4 * APW) + wave * APW;
  int np_loc = 0, nn_loc = 0; float pce_loc = 0.f, reg_loc = 0.f;
  for (int i = 0; i < APW; ++i) {
    const int a = base + i;
    const size_t idx = (size_t)b * NA_ + a;
    const float imax = iou_max_in[idx];   // broadcast load (all lanes same addr)
    const int gi = gt_idx_in[idx];
    bool pos = (imax >= 0.5f);
    if (!pos) {
      #pragma unroll
      for (int g = 0; g < NG_; ++g) pos = pos || (best_a_sh[g] == a);
    }
    const bool ign = (imax > 0.4f) && !pos;
    float ce = 0.0f;
    if (!ign) {  // wave-uniform branch; ign anchors skip the 324B row read
      const int tgt = pos ? label_sh[gi] : 0;
      const float* row = cls_pred + idx * C_;
      const float x0 = row[lane];
      const float x1 = (lane < C_ - 64) ? row[64 + lane] : -3.4e38f;
      float m = wave_max_f(fmaxf(x0, x1));
      float ss = expf(x0 - m) + ((lane < C_ - 64) ? expf(x1 - m) : 0.f);
      ss = wave_sum_f(ss);
      const float lse = m + logf(ss);
      const float xa = __shfl(x0, tgt & 63);
      const float xb = __shfl(x1, (tgt >= 64) ? (tgt - 64) : 0);
      const float xt = (tgt < 64) ? xa : xb;
      ce = lse - xt;   // >= 0 always
    }
    if (lane == 0) {
      const bool neg = !pos && !ign;
      neg_bits[idx] = neg ? __float_as_int(ce) : -1;   // -1 sentinel < all valid bits
      if (pos) {
        ++np_loc; ++nn_loc; pce_loc += ce;
        const float4 bp = ((const float4*)box_pred)[idx];
        const float4 an = ((const float4*)anchors)[a];
        const float* gt = gt_boxes + ((size_t)b * NG_ + gi) * 4;
        const float tx = (gt[0] - an.x) / an.z / 0.1f;
        const float ty = (gt[1] - an.y) / an.w / 0.1f;
        const float tw = logf(gt[2] / an.z) / 0.2f;
        const float th = logf(gt[3] / an.w) / 0.2f;
        float d, ad;
        d = bp.x - tx; ad = fabsf(d); reg_loc += (ad < 1.f) ? 0.5f * d * d : (ad - 0.5f);
        d = bp.y - ty; ad = fabsf(d); reg_loc += (ad < 1.f) ? 0.5f * d * d : (ad - 0.5f);
        d = bp.z - tw; ad = fabsf(d); reg_loc += (ad < 1.f) ? 0.5f * d * d : (ad - 0.5f);
        d = bp.w - th; ad = fabsf(d); reg_loc += (ad < 1.f) ? 0.5f * d * d : (ad - 0.5f);
      } else if (ign) ++nn_loc;
    }
  }
  if (lane == 0) { np_sh[wave] = np_loc; nn_sh[wave] = nn_loc; pce_sh[wave] = pce_loc; reg_sh[wave] = reg_loc; }
  __syncthreads();
  if (threadIdx.x == 0) {
    int np = 0, nn = 0; float pc = 0.f, rg = 0.f;
    for (int w = 0; w < 4; ++w) { np += np_sh[w]; nn += nn_sh[w]; pc += pce_sh[w]; rg += reg_sh[w]; }
    if (np) atomicAdd(&num_pos_g[b], np);
    if (nn) atomicAdd(&notneg_g[b], nn);
    if (pc != 0.f) atomicAdd(&pos_ce_g[b], pc);
    if (rg != 0.f) atomicAdd(&reg_sum_g[b], rg);
  }
}

// ---------- K4: per-batch exact top-k sum via bitwise radix select ----------
__global__ __launch_bounds__(1024) void k_select(
    const int* __restrict__ neg_bits,
    const int* __restrict__ num_pos_g, const int* __restrict__ notneg_g,
    const float* __restrict__ pos_ce_g, const float* __restrict__ reg_sum_g,
    float* __restrict__ cls_out, float* __restrict__ reg_out)
{
  const int b = blockIdx.x;
  const int t = threadIdx.x;
  const int wave = t >> 6, lane = t & 63;
  int v[32];   // all 32768 values of this batch live in block registers
  const int* src = neg_bits + (size_t)b * NA_;
  #pragma unroll
  for (int i = 0; i < 32; ++i) v[i] = src[t + (i << 10)];
  const int np = num_pos_g[b];
  const int negc = NA_ - notneg_g[b];
  const int k1 = min(3 * np, negc);
  const int k0 = min(100, negc);
  __shared__ unsigned red_sh[16];
  __shared__ unsigned bc_sh;
  int T1 = 0, T0 = 0;   // ce>=0 -> bits monotone as signed int; sentinel -1 never counted
  for (int bit = 30; bit >= 0; --bit) {
    const int t1 = T1 | (1 << bit);
    const int t0 = T0 | (1 << bit);
    unsigned c = 0;
    #pragma unroll
    for (int i = 0; i < 32; ++i) {
      if (v[i] >= t1) c += (1u << 16);
      if (v[i] >= t0) c += 1u;
    }
    #pragma unroll
    for (int s = 32; s >= 1; s >>= 1) c += __shfl_xor(c, s);
    if (lane == 0) red_sh[wave] = c;
    __syncthreads();
    if (t == 0) {
      unsigned sum = 0;
      for (int w = 0; w < 16; ++w) sum += red_sh[w];
      bc_sh = sum;
    }
    __syncthreads();
    const unsigned sum = bc_sh;
    if ((int)(sum >> 16) >= k1 && k1 > 0) T1 = t1;
    if ((int)(sum & 0xFFFFu) >= k0 && k0 > 0) T0 = t0;
    __syncthreads();
  }
  float s1 = 0.f, s0 = 0.f; unsigned cg = 0;
  #pragma unroll
  for (int i = 0; i < 32; ++i) {
    const int x = v[i];
    if (x > T1) { s1 += __int_as_float(x); cg += (1u << 16); }
    if (x > T0) { s0 += __int_as_float(x); cg += 1u; }
  }
  #pragma unroll
  for (int s = 32; s >= 1; s >>= 1) {
    s1 += __shfl_xor(s1, s); s0 += __shfl_xor(s0, s); cg += __shfl_xor(cg, s);
  }
  __shared__ float f1_sh[16], f0_sh[16]; __shared__ unsigned cg_sh[16];
  if (lane == 0) { f1_sh[wave] = s1; f0_sh[wave] = s0; cg_sh[wave] = cg; }
  __syncthreads();
  if (t == 0) {
    float S1 = 0.f, S0 = 0.f; unsigned CG = 0;
    for (int w = 0; w < 16; ++w) { S1 += f1_sh[w]; S0 += f0_sh[w]; CG += cg_sh[w]; }
    const int cg1 = (int)(CG >> 16), cg0 = (int)(CG & 0xFFFFu);
    // sum of top-k == sum(v > v_k) + (k - count_gt) * v_k  (ties handled exactly)
    const float topk1 = (k1 > 0) ? (S1 + (float)(k1 - cg1) * __int_as_float(T1)) : 0.f;
    const float topk0 = (k0 > 0) ? (S0 + (float)(k0 - cg0) * __int_as_float(T0)) : 0.f;
    const float npf = (float)np;
    const float pce = pos_ce_g[b];
    float cls;
    if (np > 0)
      cls = (k1 > 0) ? (pce + topk1) / fmaxf(npf + (float)k1, 1.f)
                     : pce / fmaxf(npf, 1.f);
    else
      cls = (k0 > 0) ? topk0 / fmaxf((float)k0, 1.f) : 0.f;
    cls_out[b] = cls;
    reg_out[b] = (np > 0) ? reg_sum_g[b] / fmaxf(npf * 4.f, 1.f) : 0.f;
  }
}

// ---------- K5: final 3-scalar reduction ----------
__global__ __launch_bounds__(64) void k_final(
    const float* __restrict__ cls_out, const float* __restrict__ reg_out,
    const int* __restrict__ num_pos_g, float* __restrict__ out)
{
  const int t = threadIdx.x;
  float c = (t < B_) ? cls_out[t] : 0.f;
  float r = (t < B_) ? reg_out[t] : 0.f;
  float n = (t < B_) ? (float)num_pos_g[t] : 0.f;
  #pragma unroll
  for (int s = 32; s >= 1; s >>= 1) {
    c += __shfl_xor(c, s); r += __shfl_xor(r, s); n += __shfl_xor(n, s);
  }
  if (t == 0) { out[0] = c / (float)B_; out[1] = r / (float)B_; out[2] = n / (float)B_; }
}

extern "C" void kernel_launch(void* const* d_in, const int* in_sizes, int n_in,
                              void* d_out, int out_size, void* d_ws, size_t ws_size,
                              hipStream_t stream) {
  const float* cls_pred  = (const float*)d_in[0];
  const float* box_pred  = (const float*)d_in[1];
  const float* anchors   = (const float*)d_in[2];
  const float* gt_boxes  = (const float*)d_in[3];
  const int*   gt_labels = (const int*)d_in[4];
  float* out = (float*)d_out;

  char* ws = (char*)d_ws;
  unsigned long long* best_packed = (unsigned long long*)ws;          // 32*24*8 = 6144 B
  int*   num_pos_g = (int*)(ws + 6144);
  int*   notneg_g  = (int*)(ws + 6144 + 128);
  float* pos_ce_g  = (float*)(ws + 6144 + 256);
  float* reg_sum_g = (float*)(ws + 6144 + 384);
  float* cls_out   = (float*)(ws + 6144 + 512);
  float* reg_out   = (float*)(ws + 6144 + 640);
  float* iou_max   = (float*)(ws + 8192);                             // 4 MB
  int*   gt_idx    = (int*)(ws + 8192 + (size_t)4 * B_ * NA_);        // 4 MB
  int*   neg_bits  = (int*)(ws + 8192 + (size_t)8 * B_ * NA_);        // 4 MB

  hipLaunchKernelGGL(k_init, dim3(1), dim3(768), 0, stream,
                     best_packed, num_pos_g, notneg_g, pos_ce_g, reg_sum_g);
  hipLaunchKernelGGL(k_match, dim3(NA_ / 256, B_), dim3(256), 0, stream,
                     anchors, gt_boxes, iou_max, gt_idx, best_packed);
  hipLaunchKernelGGL(k_ce, dim3(NA_ / 64, B_), dim3(256), 0, stream,
                     cls_pred, box_pred, anchors, gt_boxes, gt_labels,
                     iou_max, gt_idx, best_packed, neg_bits,
                     num_pos_g, notneg_g, pos_ce_g, reg_sum_g);
  hipLaunchKernelGGL(k_select, dim3(B_), dim3(1024), 0, stream,
                     neg_bits, num_pos_g, notneg_g, pos_ce_g, reg_sum_g, cls_out, reg_out);
  hipLaunchKernelGGL(k_final, dim3(1), dim3(64), 0, stream,
                     cls_out, reg_out, num_pos_g, out);
}

// Round 2
// 588.022 us; speedup vs baseline: 1.4402x; 1.4402x over previous
//
#include <hip/hip_runtime.h>
#include <math.h>

#define B_  32
#define NA_ 32768
#define C_  81
#define NG_ 24

typedef const __attribute__((address_space(1))) unsigned int* gas_ptr;
typedef __attribute__((address_space(3))) unsigned int* las_ptr;

// ---------- helpers ----------
__device__ inline float wave_max_f(float v) {
  #pragma unroll
  for (int s = 32; s >= 1; s >>= 1) v = fmaxf(v, __shfl_xor(v, s));
  return v;
}
__device__ inline float wave_sum_f(float v) {
  #pragma unroll
  for (int s = 32; s >= 1; s >>= 1) v += __shfl_xor(v, s);
  return v;
}

// ---------- K0: zero accumulators (ws is poisoned 0xAA each call) ----------
__global__ void k_init(unsigned long long* best_packed, int* num_pos_g, int* notneg_g,
                       float* pos_ce_g, float* reg_sum_g) {
  const int t = threadIdx.x + blockIdx.x * blockDim.x;
  if (t < B_ * NG_) best_packed[t] = 0ULL;
  if (t < B_) { num_pos_g[t] = 0; notneg_g[t] = 0; pos_ce_g[t] = 0.f; reg_sum_g[t] = 0.f; }
}

// ---------- K1: per-anchor IoU max/argmax + per-GT best anchor ----------
__global__ __launch_bounds__(256) void k_match(
    const float* __restrict__ anchors, const float* __restrict__ gt_boxes,
    float* __restrict__ iou_max_out, int* __restrict__ gt_idx_out,
    unsigned long long* __restrict__ best_packed)
{
  const int b = blockIdx.y;
  const int a = blockIdx.x * 256 + threadIdx.x;
  __shared__ float4 gt_sh[NG_];
  __shared__ float gt_area_sh[NG_];
  __shared__ unsigned long long best_sh[NG_];
  if (threadIdx.x < NG_) {
    const float* g = gt_boxes + ((size_t)b * NG_ + threadIdx.x) * 4;
    float cx = g[0], cy = g[1], w = g[2], h = g[3];
    float x0 = cx - 0.5f * w, y0 = cy - 0.5f * h, x1 = cx + 0.5f * w, y1 = cy + 0.5f * h;
    gt_sh[threadIdx.x] = make_float4(x0, y0, x1, y1);
    gt_area_sh[threadIdx.x] = (x1 - x0) * (y1 - y0);
    best_sh[threadIdx.x] = 0ULL;
  }
  __syncthreads();
  const float4 anc = ((const float4*)anchors)[a];
  const float ax0 = anc.x - 0.5f * anc.z, ay0 = anc.y - 0.5f * anc.w;
  const float ax1 = anc.x + 0.5f * anc.z, ay1 = anc.y + 0.5f * anc.w;
  const float area_a = (ax1 - ax0) * (ay1 - ay0);
  float best_iou = -1.0f; int best_g = 0;
  const int lane = threadIdx.x & 63;
  const int wave_base = a - lane;   // lanes hold consecutive anchors
  for (int g = 0; g < NG_; ++g) {
    const float4 G = gt_sh[g];
    float lx = fmaxf(ax0, G.x), ly = fmaxf(ay0, G.y);
    float rx = fminf(ax1, G.z), ry = fminf(ay1, G.w);
    float ww = fmaxf(rx - lx, 0.f), hh = fmaxf(ry - ly, 0.f);
    float inter = ww * hh;
    float uni = area_a + gt_area_sh[g] - inter;
    float iou = inter / fmaxf(uni, 1e-12f);
    if (iou > best_iou) { best_iou = iou; best_g = g; }   // first-max tie-break
    // wave max + first-lane-with-max = smallest anchor index on ties
    const float m = wave_max_f(iou);
    const unsigned long long mk = __ballot(iou == m);
    if (lane == 0) {
      const int amin = wave_base + (__ffsll((long long)mk) - 1);
      const unsigned long long key =
          ((unsigned long long)__float_as_uint(m) << 32) | (unsigned)(~(unsigned)amin);
      atomicMax(&best_sh[g], key);
    }
  }
  const size_t idx = (size_t)b * NA_ + a;
  iou_max_out[idx] = best_iou;
  gt_idx_out[idx]  = best_g;
  __syncthreads();
  if (threadIdx.x < NG_)
    atomicMax(&best_packed[b * NG_ + threadIdx.x], best_sh[threadIdx.x]);
}

// ---------- K2: thread-per-anchor CE via LDS tile staging ----------
#define TPB 128   // threads = anchors per block; LDS tile = 128*81*4 = 41472 B
__global__ __launch_bounds__(128) void k_ce(
    const float* __restrict__ cls_pred, const float* __restrict__ box_pred,
    const float* __restrict__ anchors, const float* __restrict__ gt_boxes,
    const int* __restrict__ gt_labels,
    const float* __restrict__ iou_max_in, const int* __restrict__ gt_idx_in,
    const unsigned long long* __restrict__ best_packed,
    int* __restrict__ neg_bits,
    int* __restrict__ num_pos_g, int* __restrict__ notneg_g,
    float* __restrict__ pos_ce_g, float* __restrict__ reg_sum_g)
{
  __shared__ float tile[TPB * C_];
  __shared__ int best_a_sh[NG_];
  __shared__ int label_sh[NG_];
  __shared__ int np_sh[2], nn_sh[2];
  __shared__ float pce_sh[2], reg_sh[2];
  const int b = blockIdx.y;
  const int tid = threadIdx.x;
  const int wave = tid >> 6, lane = tid & 63;
  const int a0 = blockIdx.x * TPB;
  const int a = a0 + tid;
  const size_t idx = (size_t)b * NA_ + a;

  if (tid < NG_) {
    best_a_sh[tid] = (int)(~(unsigned)(best_packed[b * NG_ + tid]));
    label_sh[tid]  = gt_labels[b * NG_ + tid];
  }

  // ---- stage 128 rows (contiguous 41472 B) global -> LDS, 16B chunks ----
  // chunk c (16B): global = gtile + c*16 ; LDS dest = wave-uniform base + lane*16
  {
    const unsigned int* gtile =
        (const unsigned int*)(cls_pred + ((size_t)b * NA_ + a0) * C_);
    las_ptr lbase = (las_ptr)tile;
    #pragma unroll
    for (int k = 0; k < 20; ++k) {
      const int chunk = k * TPB + tid;                  // per-lane global chunk
      const int wbase = k * TPB + wave * 64;            // wave-uniform LDS chunk base
      __builtin_amdgcn_global_load_lds((gas_ptr)(gtile + (size_t)chunk * 4),
                                       lbase + (size_t)wbase * 4, 16, 0, 0);
    }
    if (tid < 32) {   // remainder: chunks 2560..2591, wave 0 lanes 0..31
      const int chunk = 20 * TPB + tid;
      __builtin_amdgcn_global_load_lds((gas_ptr)(gtile + (size_t)chunk * 4),
                                       lbase + (size_t)(20 * TPB) * 4, 16, 0, 0);
    }
  }

  const float imax = iou_max_in[idx];   // coalesced per-thread loads
  const int gi = gt_idx_in[idx];
  __syncthreads();   // drains vmcnt (global_load_lds) + lgkm

  bool pos = (imax >= 0.5f);
  #pragma unroll
  for (int g = 0; g < NG_; ++g) pos = pos || (best_a_sh[g] == a);
  const bool ign = (imax > 0.4f) && !pos;
  const bool neg = !pos && !ign;
  const int tgt = pos ? label_sh[gi] : 0;

  // ---- single-pass logsumexp over own row (stride 81 dwords: conflict-free) ----
  const float* row = &tile[tid * C_];
  float sum = 0.f;
  #pragma unroll 27
  for (int j = 0; j < C_; ++j) sum += __expf(row[j]);
  float ce = fmaxf(__logf(sum) - row[tgt], 0.f);

  neg_bits[idx] = neg ? __float_as_int(ce) : -1;   // sentinel -1 < all valid bits

  float pce = 0.f, reg = 0.f;
  if (pos) {
    pce = ce;
    const float4 bp = ((const float4*)box_pred)[idx];
    const float4 an = ((const float4*)anchors)[a];
    const float* gt = gt_boxes + ((size_t)b * NG_ + gi) * 4;
    const float tx = (gt[0] - an.x) / an.z / 0.1f;
    const float ty = (gt[1] - an.y) / an.w / 0.1f;
    const float tw = logf(gt[2] / an.z) / 0.2f;
    const float th = logf(gt[3] / an.w) / 0.2f;
    float d, ad;
    d = bp.x - tx; ad = fabsf(d); reg += (ad < 1.f) ? 0.5f * d * d : (ad - 0.5f);
    d = bp.y - ty; ad = fabsf(d); reg += (ad < 1.f) ? 0.5f * d * d : (ad - 0.5f);
    d = bp.z - tw; ad = fabsf(d); reg += (ad < 1.f) ? 0.5f * d * d : (ad - 0.5f);
    d = bp.w - th; ad = fabsf(d); reg += (ad < 1.f) ? 0.5f * d * d : (ad - 0.5f);
  }

  // ---- block reduction: 2 waves -> LDS -> 4 atomics ----
  const int np_w = __popcll(__ballot(pos));
  const int nn_w = __popcll(__ballot(pos || ign));
  const float pce_w = wave_sum_f(pce);
  const float reg_w = wave_sum_f(reg);
  if (lane == 0) { np_sh[wave] = np_w; nn_sh[wave] = nn_w; pce_sh[wave] = pce_w; reg_sh[wave] = reg_w; }
  __syncthreads();
  if (tid == 0) {
    const int np = np_sh[0] + np_sh[1];
    const int nn = nn_sh[0] + nn_sh[1];
    const float pc = pce_sh[0] + pce_sh[1];
    const float rg = reg_sh[0] + reg_sh[1];
    if (np) atomicAdd(&num_pos_g[b], np);
    if (nn) atomicAdd(&notneg_g[b], nn);
    if (pc != 0.f) atomicAdd(&pos_ce_g[b], pc);
    if (rg != 0.f) atomicAdd(&reg_sum_g[b], rg);
  }
}

// ---------- K4: per-batch exact top-k sum via bitwise radix select ----------
__global__ __launch_bounds__(1024) void k_select(
    const int* __restrict__ neg_bits,
    const int* __restrict__ num_pos_g, const int* __restrict__ notneg_g,
    const float* __restrict__ pos_ce_g, const float* __restrict__ reg_sum_g,
    float* __restrict__ cls_out, float* __restrict__ reg_out)
{
  const int b = blockIdx.x;
  const int t = threadIdx.x;
  const int wave = t >> 6, lane = t & 63;
  int v[32];   // all 32768 values of this batch live in block registers
  const int* src = neg_bits + (size_t)b * NA_;
  #pragma unroll
  for (int i = 0; i < 32; ++i) v[i] = src[t + (i << 10)];
  const int np = num_pos_g[b];
  const int negc = NA_ - notneg_g[b];
  const int k1 = min(3 * np, negc);
  const int k0 = min(100, negc);
  __shared__ unsigned red_sh[16];
  __shared__ unsigned bc_sh;
  int T1 = 0, T0 = 0;   // ce>=0 -> bits monotone as signed int; sentinel -1 never counted
  for (int bit = 30; bit >= 0; --bit) {
    const int t1 = T1 | (1 << bit);
    const int t0 = T0 | (1 << bit);
    unsigned c = 0;
    #pragma unroll
    for (int i = 0; i < 32; ++i) {
      if (v[i] >= t1) c += (1u << 16);
      if (v[i] >= t0) c += 1u;
    }
    #pragma unroll
    for (int s = 32; s >= 1; s >>= 1) c += __shfl_xor(c, s);
    if (lane == 0) red_sh[wave] = c;
    __syncthreads();
    if (t == 0) {
      unsigned sum = 0;
      for (int w = 0; w < 16; ++w) sum += red_sh[w];
      bc_sh = sum;
    }
    __syncthreads();
    const unsigned sum = bc_sh;
    if ((int)(sum >> 16) >= k1 && k1 > 0) T1 = t1;
    if ((int)(sum & 0xFFFFu) >= k0 && k0 > 0) T0 = t0;
    __syncthreads();
  }
  float s1 = 0.f, s0 = 0.f; unsigned cg = 0;
  #pragma unroll
  for (int i = 0; i < 32; ++i) {
    const int x = v[i];
    if (x > T1) { s1 += __int_as_float(x); cg += (1u << 16); }
    if (x > T0) { s0 += __int_as_float(x); cg += 1u; }
  }
  #pragma unroll
  for (int s = 32; s >= 1; s >>= 1) {
    s1 += __shfl_xor(s1, s); s0 += __shfl_xor(s0, s); cg += __shfl_xor(cg, s);
  }
  __shared__ float f1_sh[16], f0_sh[16]; __shared__ unsigned cg_sh[16];
  if (lane == 0) { f1_sh[wave] = s1; f0_sh[wave] = s0; cg_sh[wave] = cg; }
  __syncthreads();
  if (t == 0) {
    float S1 = 0.f, S0 = 0.f; unsigned CG = 0;
    for (int w = 0; w < 16; ++w) { S1 += f1_sh[w]; S0 += f0_sh[w]; CG += cg_sh[w]; }
    const int cg1 = (int)(CG >> 16), cg0 = (int)(CG & 0xFFFFu);
    // sum of top-k == sum(v > v_k) + (k - count_gt) * v_k  (ties handled exactly)
    const float topk1 = (k1 > 0) ? (S1 + (float)(k1 - cg1) * __int_as_float(T1)) : 0.f;
    const float topk0 = (k0 > 0) ? (S0 + (float)(k0 - cg0) * __int_as_float(T0)) : 0.f;
    const float npf = (float)np;
    const float pce = pos_ce_g[b];
    float cls;
    if (np > 0)
      cls = (k1 > 0) ? (pce + topk1) / fmaxf(npf + (float)k1, 1.f)
                     : pce / fmaxf(npf, 1.f);
    else
      cls = (k0 > 0) ? topk0 / fmaxf((float)k0, 1.f) : 0.f;
    cls_out[b] = cls;
    reg_out[b] = (np > 0) ? reg_sum_g[b] / fmaxf(npf * 4.f, 1.f) : 0.f;
  }
}

// ---------- K5: final 3-scalar reduction ----------
__global__ __launch_bounds__(64) void k_final(
    const float* __restrict__ cls_out, const float* __restrict__ reg_out,
    const int* __restrict__ num_pos_g, float* __restrict__ out)
{
  const int t = threadIdx.x;
  float c = (t < B_) ? cls_out[t] : 0.f;
  float r = (t < B_) ? reg_out[t] : 0.f;
  float n = (t < B_) ? (float)num_pos_g[t] : 0.f;
  #pragma unroll
  for (int s = 32; s >= 1; s >>= 1) {
    c += __shfl_xor(c, s); r += __shfl_xor(r, s); n += __shfl_xor(n, s);
  }
  if (t == 0) { out[0] = c / (float)B_; out[1] = r / (float)B_; out[2] = n / (float)B_; }
}

extern "C" void kernel_launch(void* const* d_in, const int* in_sizes, int n_in,
                              void* d_out, int out_size, void* d_ws, size_t ws_size,
                              hipStream_t stream) {
  const float* cls_pred  = (const float*)d_in[0];
  const float* box_pred  = (const float*)d_in[1];
  const float* anchors   = (const float*)d_in[2];
  const float* gt_boxes  = (const float*)d_in[3];
  const int*   gt_labels = (const int*)d_in[4];
  float* out = (float*)d_out;

  char* ws = (char*)d_ws;
  unsigned long long* best_packed = (unsigned long long*)ws;          // 32*24*8 = 6144 B
  int*   num_pos_g = (int*)(ws + 6144);
  int*   notneg_g  = (int*)(ws + 6144 + 128);
  float* pos_ce_g  = (float*)(ws + 6144 + 256);
  float* reg_sum_g = (float*)(ws + 6144 + 384);
  float* cls_out   = (float*)(ws + 6144 + 512);
  float* reg_out   = (float*)(ws + 6144 + 640);
  float* iou_max   = (float*)(ws + 8192);                             // 4 MB
  int*   gt_idx    = (int*)(ws + 8192 + (size_t)4 * B_ * NA_);        // 4 MB
  int*   neg_bits  = (int*)(ws + 8192 + (size_t)8 * B_ * NA_);        // 4 MB

  hipLaunchKernelGGL(k_init, dim3(1), dim3(768), 0, stream,
                     best_packed, num_pos_g, notneg_g, pos_ce_g, reg_sum_g);
  hipLaunchKernelGGL(k_match, dim3(NA_ / 256, B_), dim3(256), 0, stream,
                     anchors, gt_boxes, iou_max, gt_idx, best_packed);
  hipLaunchKernelGGL(k_ce, dim3(NA_ / TPB, B_), dim3(TPB), 0, stream,
                     cls_pred, box_pred, anchors, gt_boxes, gt_labels,
                     iou_max, gt_idx, best_packed, neg_bits,
                     num_pos_g, notneg_g, pos_ce_g, reg_sum_g);
  hipLaunchKernelGGL(k_select, dim3(B_), dim3(1024), 0, stream,
                     neg_bits, num_pos_g, notneg_g, pos_ce_g, reg_sum_g, cls_out, reg_out);
  hipLaunchKernelGGL(k_final, dim3(1), dim3(64), 0, stream,
                     cls_out, reg_out, num_pos_g, out);
}

// Round 3
// 584.330 us; speedup vs baseline: 1.4493x; 1.0063x over previous
//
#include <hip/hip_runtime.h>
#include <math.h>

#define B_  32
#define NA_ 32768
#define C_  81
#define NG_ 24

typedef const __attribute__((address_space(1))) unsigned int* gas_ptr;
typedef __attribute__((address_space(3))) unsigned int* las_ptr;

// ---------- helpers ----------
__device__ inline float wave_sum_f(float v) {
  #pragma unroll
  for (int s = 32; s >= 1; s >>= 1) v += __shfl_xor(v, s);
  return v;
}
__device__ inline unsigned long long shflx_u64(unsigned long long v, int s) {
  int lo = __shfl_xor((int)(unsigned)(v & 0xFFFFFFFFULL), s);
  int hi = __shfl_xor((int)(unsigned)(v >> 32), s);
  return ((unsigned long long)(unsigned)hi << 32) | (unsigned)lo;
}

// ---------- K1a: per-anchor IoU max / argmax over GTs (no cross-lane ops) ----------
__global__ __launch_bounds__(256) void k_match_a(
    const float* __restrict__ anchors, const float* __restrict__ gt_boxes,
    float* __restrict__ iou_max_out, int* __restrict__ gt_idx_out)
{
  const int b = blockIdx.y;
  const int a = blockIdx.x * 256 + threadIdx.x;
  __shared__ float4 gt_sh[NG_];
  __shared__ float gt_area_sh[NG_];
  if (threadIdx.x < NG_) {
    const float* g = gt_boxes + ((size_t)b * NG_ + threadIdx.x) * 4;
    float cx = g[0], cy = g[1], w = g[2], h = g[3];
    float x0 = cx - 0.5f * w, y0 = cy - 0.5f * h, x1 = cx + 0.5f * w, y1 = cy + 0.5f * h;
    gt_sh[threadIdx.x] = make_float4(x0, y0, x1, y1);
    gt_area_sh[threadIdx.x] = (x1 - x0) * (y1 - y0);
  }
  __syncthreads();
  const float4 anc = ((const float4*)anchors)[a];
  const float ax0 = anc.x - 0.5f * anc.z, ay0 = anc.y - 0.5f * anc.w;
  const float ax1 = anc.x + 0.5f * anc.z, ay1 = anc.y + 0.5f * anc.w;
  const float area_a = (ax1 - ax0) * (ay1 - ay0);
  float best_iou = -1.0f; int best_g = 0;
  #pragma unroll 4
  for (int g = 0; g < NG_; ++g) {
    const float4 G = gt_sh[g];
    float lx = fmaxf(ax0, G.x), ly = fmaxf(ay0, G.y);
    float rx = fminf(ax1, G.z), ry = fminf(ay1, G.w);
    float ww = fmaxf(rx - lx, 0.f), hh = fmaxf(ry - ly, 0.f);
    float inter = ww * hh;
    float uni = area_a + gt_area_sh[g] - inter;
    float iou = inter / fmaxf(uni, 1e-12f);
    if (iou > best_iou) { best_iou = iou; best_g = g; }   // first-max tie-break
  }
  const size_t idx = (size_t)b * NA_ + a;
  iou_max_out[idx] = best_iou;
  gt_idx_out[idx]  = best_g;
}

// ---------- K1b: one block per (gt, batch): full argmax over anchors ----------
// Also zeroes the accumulators + out (block (0,0)); plain store, no atomics.
__global__ __launch_bounds__(256) void k_match_b(
    const float* __restrict__ anchors, const float* __restrict__ gt_boxes,
    int* __restrict__ best_anchor,
    int* num_pos_g, int* notneg_g, float* pos_ce_g, float* reg_sum_g, float* out)
{
  const int g = blockIdx.x, b = blockIdx.y;
  const int tid = threadIdx.x, wave = tid >> 6, lane = tid & 63;
  if (g == 0 && b == 0) {
    if (tid < B_) { num_pos_g[tid] = 0; notneg_g[tid] = 0; pos_ce_g[tid] = 0.f; reg_sum_g[tid] = 0.f; }
    else if (tid < B_ + 3) out[tid - B_] = 0.f;
  }
  const float* gp = gt_boxes + ((size_t)b * NG_ + g) * 4;
  const float gx0 = gp[0] - 0.5f * gp[2], gy0 = gp[1] - 0.5f * gp[3];
  const float gx1 = gp[0] + 0.5f * gp[2], gy1 = gp[1] + 0.5f * gp[3];
  const float area_g = (gx1 - gx0) * (gy1 - gy0);
  unsigned long long key = 0ULL;   // (iou_bits<<32) | ~a  : max => first-max anchor
  #pragma unroll 4
  for (int i = 0; i < NA_ / 256; ++i) {
    const int a = i * 256 + tid;                 // increasing a per thread
    const float4 anc = ((const float4*)anchors)[a];
    const float ax0 = anc.x - 0.5f * anc.z, ay0 = anc.y - 0.5f * anc.w;
    const float ax1 = anc.x + 0.5f * anc.z, ay1 = anc.y + 0.5f * anc.w;
    float lx = fmaxf(ax0, gx0), ly = fmaxf(ay0, gy0);
    float rx = fminf(ax1, gx1), ry = fminf(ay1, gy1);
    float ww = fmaxf(rx - lx, 0.f), hh = fmaxf(ry - ly, 0.f);
    float inter = ww * hh;
    float uni = (ax1 - ax0) * (ay1 - ay0) + area_g - inter;
    float iou = inter / fmaxf(uni, 1e-12f);
    unsigned long long k2 =
        ((unsigned long long)__float_as_uint(iou) << 32) | (unsigned)(~(unsigned)a);
    if (k2 > key) key = k2;
  }
  #pragma unroll
  for (int s = 32; s >= 1; s >>= 1) {
    unsigned long long o = shflx_u64(key, s);
    if (o > key) key = o;
  }
  __shared__ unsigned long long red[4];
  if (lane == 0) red[wave] = key;
  __syncthreads();
  if (tid == 0) {
    unsigned long long k = red[0];
    for (int w = 1; w < 4; ++w) if (red[w] > k) k = red[w];
    best_anchor[b * NG_ + g] = (int)(~(unsigned)k);
  }
}

// ---------- K2: thread-per-anchor CE via LDS tile staging ----------
#define TPB 128   // threads = anchors per block; LDS tile = 128*81*4 = 41472 B
__global__ __launch_bounds__(128) void k_ce(
    const float* __restrict__ cls_pred, const float* __restrict__ box_pred,
    const float* __restrict__ anchors, const float* __restrict__ gt_boxes,
    const int* __restrict__ gt_labels,
    const float* __restrict__ iou_max_in, const int* __restrict__ gt_idx_in,
    const int* __restrict__ best_anchor,
    int* __restrict__ neg_bits,
    int* __restrict__ num_pos_g, int* __restrict__ notneg_g,
    float* __restrict__ pos_ce_g, float* __restrict__ reg_sum_g)
{
  __shared__ float tile[TPB * C_];
  __shared__ int best_a_sh[NG_];
  __shared__ int label_sh[NG_];
  __shared__ int np_sh[2], nn_sh[2];
  __shared__ float pce_sh[2], reg_sh[2];
  const int b = blockIdx.y;
  const int tid = threadIdx.x;
  const int wave = tid >> 6, lane = tid & 63;
  const int a0 = blockIdx.x * TPB;
  const int a = a0 + tid;
  const size_t idx = (size_t)b * NA_ + a;

  if (tid < NG_) {
    best_a_sh[tid] = best_anchor[b * NG_ + tid];
    label_sh[tid]  = gt_labels[b * NG_ + tid];
  }

  // ---- stage 128 rows (contiguous 41472 B) global -> LDS, 16B chunks ----
  {
    const unsigned int* gtile =
        (const unsigned int*)(cls_pred + ((size_t)b * NA_ + a0) * C_);
    las_ptr lbase = (las_ptr)tile;
    #pragma unroll
    for (int k = 0; k < 20; ++k) {
      const int chunk = k * TPB + tid;                  // per-lane global chunk
      const int wbase = k * TPB + wave * 64;            // wave-uniform LDS chunk base
      __builtin_amdgcn_global_load_lds((gas_ptr)(gtile + (size_t)chunk * 4),
                                       lbase + (size_t)wbase * 4, 16, 0, 0);
    }
    if (tid < 32) {   // remainder: chunks 2560..2591, wave 0 lanes 0..31
      const int chunk = 20 * TPB + tid;
      __builtin_amdgcn_global_load_lds((gas_ptr)(gtile + (size_t)chunk * 4),
                                       lbase + (size_t)(20 * TPB) * 4, 16, 0, 0);
    }
  }

  const float imax = iou_max_in[idx];   // coalesced per-thread loads
  const int gi = gt_idx_in[idx];
  __syncthreads();   // drains vmcnt (global_load_lds) + lgkm

  bool pos = (imax >= 0.5f);
  #pragma unroll
  for (int g = 0; g < NG_; ++g) pos = pos || (best_a_sh[g] == a);
  const bool ign = (imax > 0.4f) && !pos;
  const bool neg = !pos && !ign;
  const int tgt = pos ? label_sh[gi] : 0;

  // ---- single-pass logsumexp over own row (stride 81 dwords: conflict-free) ----
  const float* row = &tile[tid * C_];
  float sum = 0.f;
  #pragma unroll 27
  for (int j = 0; j < C_; ++j) sum += __expf(row[j]);
  float ce = fmaxf(__logf(sum) - row[tgt], 0.f);

  neg_bits[idx] = neg ? __float_as_int(ce) : -1;   // sentinel -1 < all valid bits

  float pce = 0.f, reg = 0.f;
  if (pos) {
    pce = ce;
    const float4 bp = ((const float4*)box_pred)[idx];
    const float4 an = ((const float4*)anchors)[a];
    const float* gt = gt_boxes + ((size_t)b * NG_ + gi) * 4;
    const float tx = (gt[0] - an.x) / an.z / 0.1f;
    const float ty = (gt[1] - an.y) / an.w / 0.1f;
    const float tw = logf(gt[2] / an.z) / 0.2f;
    const float th = logf(gt[3] / an.w) / 0.2f;
    float d, ad;
    d = bp.x - tx; ad = fabsf(d); reg += (ad < 1.f) ? 0.5f * d * d : (ad - 0.5f);
    d = bp.y - ty; ad = fabsf(d); reg += (ad < 1.f) ? 0.5f * d * d : (ad - 0.5f);
    d = bp.z - tw; ad = fabsf(d); reg += (ad < 1.f) ? 0.5f * d * d : (ad - 0.5f);
    d = bp.w - th; ad = fabsf(d); reg += (ad < 1.f) ? 0.5f * d * d : (ad - 0.5f);
  }

  // ---- block reduction: 2 waves -> LDS -> 4 atomics ----
  const int np_w = __popcll(__ballot(pos));
  const int nn_w = __popcll(__ballot(pos || ign));
  const float pce_w = wave_sum_f(pce);
  const float reg_w = wave_sum_f(reg);
  if (lane == 0) { np_sh[wave] = np_w; nn_sh[wave] = nn_w; pce_sh[wave] = pce_w; reg_sh[wave] = reg_w; }
  __syncthreads();
  if (tid == 0) {
    const int np = np_sh[0] + np_sh[1];
    const int nn = nn_sh[0] + nn_sh[1];
    const float pc = pce_sh[0] + pce_sh[1];
    const float rg = reg_sh[0] + reg_sh[1];
    if (np) atomicAdd(&num_pos_g[b], np);
    if (nn) atomicAdd(&notneg_g[b], nn);
    if (pc != 0.f) atomicAdd(&pos_ce_g[b], pc);
    if (rg != 0.f) atomicAdd(&reg_sum_g[b], rg);
  }
}

// ---------- K4: per-batch exact top-k sum via bitwise radix select + final ----------
__global__ __launch_bounds__(1024) void k_select(
    const int* __restrict__ neg_bits,
    const int* __restrict__ num_pos_g, const int* __restrict__ notneg_g,
    const float* __restrict__ pos_ce_g, const float* __restrict__ reg_sum_g,
    float* __restrict__ out)
{
  const int b = blockIdx.x;
  const int t = threadIdx.x;
  const int wave = t >> 6, lane = t & 63;
  __shared__ unsigned cnt_sh[32];            // one pre-zeroed counter per bit
  __shared__ float f1_sh[16], f0_sh[16];
  __shared__ unsigned cg_sh[16];
  if (t < 32) cnt_sh[t] = 0;
  int v[32];   // all 32768 values of this batch live in block registers
  const int4* src4 = (const int4*)(neg_bits + (size_t)b * NA_);
  #pragma unroll
  for (int i = 0; i < 8; ++i) *(int4*)&v[4 * i] = src4[t + (i << 10)];   // coalesced 16B/lane
  const int np = num_pos_g[b];
  const int negc = NA_ - notneg_g[b];
  const int k1 = min(3 * np, negc);
  const int k0 = min(100, negc);
  __syncthreads();   // cnt_sh zeroed before first atomic
  int T1 = 0, T0 = 0;   // ce>=0 -> bits monotone as signed int; sentinel -1 never counted
  for (int bit = 30; bit >= 0; --bit) {
    const int t1 = T1 | (1 << bit);
    const int t0 = T0 | (1 << bit);
    unsigned c = 0;
    #pragma unroll
    for (int i = 0; i < 32; ++i) {
      if (v[i] >= t1) c += (1u << 16);
      if (v[i] >= t0) c += 1u;
    }
    #pragma unroll
    for (int s = 32; s >= 1; s >>= 1) c += __shfl_xor(c, s);
    if (lane == 0) atomicAdd(&cnt_sh[bit], c);
    __syncthreads();                          // one barrier per bit
    const unsigned sum = cnt_sh[bit];
    if ((int)(sum >> 16) >= k1 && k1 > 0) T1 = t1;
    if ((int)(sum & 0xFFFFu) >= k0 && k0 > 0) T0 = t0;
  }
  float s1 = 0.f, s0 = 0.f; unsigned cg = 0;
  #pragma unroll
  for (int i = 0; i < 32; ++i) {
    const int x = v[i];
    if (x > T1) { s1 += __int_as_float(x); cg += (1u << 16); }
    if (x > T0) { s0 += __int_as_float(x); cg += 1u; }
  }
  #pragma unroll
  for (int s = 32; s >= 1; s >>= 1) {
    s1 += __shfl_xor(s1, s); s0 += __shfl_xor(s0, s); cg += __shfl_xor(cg, s);
  }
  if (lane == 0) { f1_sh[wave] = s1; f0_sh[wave] = s0; cg_sh[wave] = cg; }
  __syncthreads();
  if (t == 0) {
    float S1 = 0.f, S0 = 0.f; unsigned CG = 0;
    for (int w = 0; w < 16; ++w) { S1 += f1_sh[w]; S0 += f0_sh[w]; CG += cg_sh[w]; }
    const int cg1 = (int)(CG >> 16), cg0 = (int)(CG & 0xFFFFu);
    // sum of top-k == sum(v > v_k) + (k - count_gt) * v_k  (ties handled exactly)
    const float topk1 = (k1 > 0) ? (S1 + (float)(k1 - cg1) * __int_as_float(T1)) : 0.f;
    const float topk0 = (k0 > 0) ? (S0 + (float)(k0 - cg0) * __int_as_float(T0)) : 0.f;
    const float npf = (float)np;
    const float pce = pos_ce_g[b];
    float cls;
    if (np > 0)
      cls = (k1 > 0) ? (pce + topk1) / fmaxf(npf + (float)k1, 1.f)
                     : pce / fmaxf(npf, 1.f);
    else
      cls = (k0 > 0) ? topk0 / fmaxf((float)k0, 1.f) : 0.f;
    const float reg = (np > 0) ? reg_sum_g[b] / fmaxf(npf * 4.f, 1.f) : 0.f;
    // fused final reduction: out pre-zeroed by k_match_b block (0,0)
    atomicAdd(&out[0], cls * (1.0f / B_));
    atomicAdd(&out[1], reg * (1.0f / B_));
    atomicAdd(&out[2], npf * (1.0f / B_));   // exact: multiples of 1/32, sum < 2^11
  }
}

extern "C" void kernel_launch(void* const* d_in, const int* in_sizes, int n_in,
                              void* d_out, int out_size, void* d_ws, size_t ws_size,
                              hipStream_t stream) {
  const float* cls_pred  = (const float*)d_in[0];
  const float* box_pred  = (const float*)d_in[1];
  const float* anchors   = (const float*)d_in[2];
  const float* gt_boxes  = (const float*)d_in[3];
  const int*   gt_labels = (const int*)d_in[4];
  float* out = (float*)d_out;

  char* ws = (char*)d_ws;
  int*   best_anchor = (int*)ws;                                      // 32*24*4 B
  int*   num_pos_g = (int*)(ws + 6144);
  int*   notneg_g  = (int*)(ws + 6144 + 128);
  float* pos_ce_g  = (float*)(ws + 6144 + 256);
  float* reg_sum_g = (float*)(ws + 6144 + 384);
  float* iou_max   = (float*)(ws + 8192);                             // 4 MB
  int*   gt_idx    = (int*)(ws + 8192 + (size_t)4 * B_ * NA_);        // 4 MB
  int*   neg_bits  = (int*)(ws + 8192 + (size_t)8 * B_ * NA_);        // 4 MB

  hipLaunchKernelGGL(k_match_a, dim3(NA_ / 256, B_), dim3(256), 0, stream,
                     anchors, gt_boxes, iou_max, gt_idx);
  hipLaunchKernelGGL(k_match_b, dim3(NG_, B_), dim3(256), 0, stream,
                     anchors, gt_boxes, best_anchor,
                     num_pos_g, notneg_g, pos_ce_g, reg_sum_g, out);
  hipLaunchKernelGGL(k_ce, dim3(NA_ / TPB, B_), dim3(TPB), 0, stream,
                     cls_pred, box_pred, anchors, gt_boxes, gt_labels,
                     iou_max, gt_idx, best_anchor, neg_bits,
                     num_pos_g, notneg_g, pos_ce_g, reg_sum_g);
  hipLaunchKernelGGL(k_select, dim3(B_), dim3(1024), 0, stream,
                     neg_bits, num_pos_g, notneg_g, pos_ce_g, reg_sum_g, out);
}